// Round 12
// baseline (93.693 us; speedup 1.0000x reference)
//
#include <hip/hip_runtime.h>

#define NN 100000
#define NE 600000
#define D 128
#define CW 16          // packed count words per node (125 x 4-bit)

// workspace byte offsets (r9 values, verbatim)
#define OFF_CNTF   6400000    // [NN][16] f32 marginals (6.4 MB)
#define OFF_WSPLIT 38424576   // [2][128][128] bf16 W hi/lo (64 KB)

typedef __attribute__((ext_vector_type(8))) short bf16x8;
typedef __attribute__((ext_vector_type(4))) float f32x4;

__device__ __forceinline__ unsigned short f2bf(float x) {
    unsigned u = __float_as_uint(x);
    u += 0x7FFFu + ((u >> 16) & 1u);   // RNE
    return (unsigned short)(u >> 16);
}
__device__ __forceinline__ float bf2f(unsigned short s) {
    return __uint_as_float(((unsigned)s) << 16);
}
__device__ __forceinline__ unsigned pack2(unsigned short a, unsigned short b) {
    return (unsigned)a | ((unsigned)b << 16);
}

// ---------------------------------------------------------------------------
// prep: zero counts + W hi/lo bf16 split (r9 verbatim)
// ---------------------------------------------------------------------------
__global__ __launch_bounds__(256) void prep_kernel(const float* __restrict__ W,
                                                   unsigned char* __restrict__ ws) {
    int bid = blockIdx.x;
    if (bid < 1563) {
        int c = bid * 256 + threadIdx.x;            // int4 index into counts
        if (c < 400000) reinterpret_cast<int4*>(ws)[c] = make_int4(0, 0, 0, 0);
    } else {
        int idx = (bid - 1563) * 256 + threadIdx.x; // 0..16383
        float w = W[idx];
        unsigned short hi = f2bf(w);
        unsigned short lo = f2bf(w - bf2f(hi));
        unsigned short* wsplit = (unsigned short*)(ws + OFF_WSPLIT);
        wsplit[idx] = hi;
        wsplit[16384 + idx] = lo;
    }
}

// ---------------------------------------------------------------------------
// hist: ONE packed atomic per edge (combo nibbles), 4 edges/thread (r9 verbatim)
// ---------------------------------------------------------------------------
__global__ __launch_bounds__(256) void hist_kernel(const int* __restrict__ ef,
                                                   const int* __restrict__ dst,
                                                   unsigned* __restrict__ counts) {
    int g = blockIdx.x * 256 + threadIdx.x;        // 4-edge group
    if (g >= NE / 4) return;
    int4 d4 = reinterpret_cast<const int4*>(dst)[g];
    int4 f0 = reinterpret_cast<const int4*>(ef)[g * 3 + 0];
    int4 f1 = reinterpret_cast<const int4*>(ef)[g * 3 + 1];
    int4 f2 = reinterpret_cast<const int4*>(ef)[g * 3 + 2];
    int fa[12] = {f0.x, f0.y, f0.z, f0.w, f1.x, f1.y, f1.z, f1.w,
                  f2.x, f2.y, f2.z, f2.w};
    int dd[4] = {d4.x, d4.y, d4.z, d4.w};
    #pragma unroll
    for (int i = 0; i < 4; ++i) {
        int combo = fa[i * 3] * 25 + fa[i * 3 + 1] * 5 + fa[i * 3 + 2];
        atomicAdd(counts + dd[i] * CW + (combo >> 3), 1u << ((combo & 7) * 4));
    }
}

// ---------------------------------------------------------------------------
// expand: unpack 125 combo nibbles -> 15 f32 marginals (+pad) per node (r9)
// ---------------------------------------------------------------------------
__global__ __launch_bounds__(256) void expand_kernel(const unsigned* __restrict__ counts,
                                                     float* __restrict__ cntf) {
    int n = blockIdx.x * 256 + threadIdx.x;
    if (n >= NN) return;
    const unsigned* row = counts + n * CW;
    unsigned wd[16];
    #pragma unroll
    for (int i = 0; i < 4; ++i) {
        uint4 v = reinterpret_cast<const uint4*>(row)[i];
        wd[i * 4] = v.x; wd[i * 4 + 1] = v.y; wd[i * 4 + 2] = v.z; wd[i * 4 + 3] = v.w;
    }
    int mi[15];
    #pragma unroll
    for (int j = 0; j < 15; ++j) mi[j] = 0;
    #pragma unroll
    for (int c = 0; c < 125; ++c) {
        int cnt = (int)((wd[c >> 3] >> ((c & 7) * 4)) & 0xFu);
        mi[c / 25] += cnt;
        mi[5 + (c / 5) % 5] += cnt;
        mi[10 + c % 5] += cnt;
    }
    float* frow = cntf + n * 16;
    float4 o;
    o.x = (float)mi[0];  o.y = (float)mi[1];  o.z = (float)mi[2];  o.w = (float)mi[3];
    reinterpret_cast<float4*>(frow)[0] = o;
    o.x = (float)mi[4];  o.y = (float)mi[5];  o.z = (float)mi[6];  o.w = (float)mi[7];
    reinterpret_cast<float4*>(frow)[1] = o;
    o.x = (float)mi[8];  o.y = (float)mi[9];  o.z = (float)mi[10]; o.w = (float)mi[11];
    reinterpret_cast<float4*>(frow)[2] = o;
    o.x = (float)mi[12]; o.y = (float)mi[13]; o.z = (float)mi[14]; o.w = 0.0f;
    reinterpret_cast<float4*>(frow)[3] = o;
}

// ---------------------------------------------------------------------------
// gemm_fused: r9 gemm_kernel with the A-staging block computing hs in place.
// Tile 128 nodes x 64 cols (grid 1564). __launch_bounds__(512) — r9 verbatim.
// LDS: sW 32K + sA 32K + sE 7.5K + sM 8K = 79.5 KB.
// ---------------------------------------------------------------------------
__global__ __launch_bounds__(512) void gemm_kernel(const float* __restrict__ h,
                                                   const float* __restrict__ cntf,
                                                   const float* __restrict__ emb,
                                                   const unsigned short* __restrict__ wsplit,
                                                   const float* __restrict__ bias,
                                                   float* __restrict__ out) {
    __shared__ unsigned short sW[2][64 * 128];     // 32 KB, swizzled
    __shared__ unsigned short sA[128 * 128];       // 32 KB, swizzled
    __shared__ float sE[15 * 128];                 // 7.5 KB
    __shared__ float sM[128 * 16];                 // 8 KB

    const int bid  = blockIdx.x;
    const int n0   = (bid >> 1) * 128;
    const int c0   = (bid & 1) * 64;
    const int t    = threadIdx.x;
    const int lane = t & 63;
    const int w    = t >> 6;
    const int lr   = lane & 15;
    const int lg   = lane >> 4;
    char* sWb = (char*)sW;
    char* sAb = (char*)sA;

    // --- stage W (64 cols, hi+lo): 2048 x 16B chunks, swizzled (r9 verbatim)
    #pragma unroll
    for (int i = 0; i < 4; ++i) {
        int c  = t + i * 512;                      // 0..2047
        int p  = c >> 10;
        int r  = (c >> 4) & 63;
        int kc = c & 15;
        uint4 v = *reinterpret_cast<const uint4*>(wsplit + p * 16384 + (c0 + r) * 128 + kc * 8);
        int byte = p * 16384 + r * 256 + ((kc * 16) ^ ((r & 7) << 4));
        *reinterpret_cast<uint4*>(sWb + byte) = v;
    }
    // --- stage E (15 used rows of bond_emb), r9 hs_kernel loop form ---
    for (int i = t; i < 480; i += 512) {
        int r = i >> 5, c = i & 31;
        int f = r / 5, vv = r - f * 5;
        reinterpret_cast<float4*>(sE)[r * 32 + c] =
            reinterpret_cast<const float4*>(emb + (f * 8 + vv) * D)[c];
    }
    // --- stage marginals: dumb coalesced scalar loop ---
    for (int i = t; i < 128 * 16; i += 512) {
        int node = n0 + (i >> 4);
        sM[i] = (node < NN) ? cntf[node * 16 + (i & 15)] : 0.0f;
    }
    __syncthreads();

    // --- stage A: compute hs in place (r9 hs_kernel math), swizzled write ---
    {
        const int rg   = t >> 4;         // 0..31
        const int row0 = rg * 4;
        const int dq   = t & 15;         // 0..15
        const int d0   = dq * 8;

        float s[4][8];
        #pragma unroll
        for (int r = 0; r < 4; ++r)
            #pragma unroll
            for (int e = 0; e < 8; ++e) s[r][e] = 0.0f;

        #pragma unroll
        for (int j = 0; j < 15; ++j) {
            float4 e0 = *reinterpret_cast<const float4*>(&sE[j * 128 + d0]);
            float4 e1 = *reinterpret_cast<const float4*>(&sE[j * 128 + d0 + 4]);
            #pragma unroll
            for (int r = 0; r < 4; ++r) {
                float m = sM[(row0 + r) * 16 + j];
                s[r][0] += m * e0.x; s[r][1] += m * e0.y;
                s[r][2] += m * e0.z; s[r][3] += m * e0.w;
                s[r][4] += m * e1.x; s[r][5] += m * e1.y;
                s[r][6] += m * e1.z; s[r][7] += m * e1.w;
            }
        }
        #pragma unroll
        for (int r = 0; r < 4; ++r) {
            int node = n0 + row0 + r;
            float hv[8];
            if (node < NN) {
                float4 h0 = *reinterpret_cast<const float4*>(h + node * D + d0);
                float4 h1 = *reinterpret_cast<const float4*>(h + node * D + d0 + 4);
                hv[0] = h0.x; hv[1] = h0.y; hv[2] = h0.z; hv[3] = h0.w;
                hv[4] = h1.x; hv[5] = h1.y; hv[6] = h1.z; hv[7] = h1.w;
            } else {
                #pragma unroll
                for (int e = 0; e < 8; ++e) hv[e] = 0.0f;
            }
            unsigned short o[8];
            #pragma unroll
            for (int e = 0; e < 8; ++e) o[e] = f2bf(hv[e] * s[r][e]);
            uint4 uo;
            uo.x = pack2(o[0], o[1]); uo.y = pack2(o[2], o[3]);
            uo.z = pack2(o[4], o[5]); uo.w = pack2(o[6], o[7]);
            int row  = row0 + r;
            int byte = row * 256 + ((dq * 16) ^ ((row & 7) << 4));
            *reinterpret_cast<uint4*>(sAb + byte) = uo;
        }
    }
    __syncthreads();

    // --- GEMM (r9 verbatim): wave w = 16 nodes x 64 cols, 2-pass hi/lo ---
    f32x4 acc[4];
    #pragma unroll
    for (int jb = 0; jb < 4; ++jb) {
        float bv = bias[c0 + jb * 16 + lr];
        f32x4 tt = {bv, bv, bv, bv};
        acc[jb] = tt;
    }

    const int arow = w * 16 + lr;
    #pragma unroll
    for (int kk = 0; kk < 4; ++kk) {
        int abyte = arow * 256 + ((kk * 64 + lg * 16) ^ ((arow & 7) << 4));
        bf16x8 av = *reinterpret_cast<const bf16x8*>(sAb + abyte);
        #pragma unroll
        for (int jb = 0; jb < 4; ++jb) {
            int brow  = jb * 16 + lr;
            int wbyte = brow * 256 + ((kk * 64 + lg * 16) ^ ((brow & 7) << 4));
            bf16x8 wh = *reinterpret_cast<const bf16x8*>(sWb + wbyte);
            bf16x8 wl = *reinterpret_cast<const bf16x8*>(sWb + 16384 + wbyte);
            acc[jb] = __builtin_amdgcn_mfma_f32_16x16x32_bf16(av, wh, acc[jb], 0, 0, 0);
            acc[jb] = __builtin_amdgcn_mfma_f32_16x16x32_bf16(av, wl, acc[jb], 0, 0, 0);
        }
    }

    // --- store (r9 verbatim) ---
    #pragma unroll
    for (int jb = 0; jb < 4; ++jb) {
        int col = c0 + jb * 16 + lr;
        #pragma unroll
        for (int r = 0; r < 4; ++r) {
            int node = n0 + w * 16 + lg * 4 + r;
            if (node < NN) out[node * D + col] = acc[jb][r];
        }
    }
}

extern "C" void kernel_launch(void* const* d_in, const int* in_sizes, int n_in,
                              void* d_out, int out_size, void* d_ws, size_t ws_size,
                              hipStream_t stream) {
    const float* h   = (const float*)d_in[0];
    const int*   ef  = (const int*)d_in[1];
    const int*   dst = (const int*)d_in[2];
    const float* emb = (const float*)d_in[3];
    const float* W   = (const float*)d_in[4];
    const float* b   = (const float*)d_in[5];
    float*       out = (float*)d_out;

    unsigned char*  ws     = (unsigned char*)d_ws;
    unsigned*       counts = (unsigned*)ws;                      // 6.4 MB
    float*          cntf   = (float*)(ws + OFF_CNTF);            // 6.4 MB
    unsigned short* wsplit = (unsigned short*)(ws + OFF_WSPLIT); // 64 KB

    prep_kernel<<<1563 + 64, 256, 0, stream>>>(W, ws);
    hist_kernel<<<(NE / 4 + 255) / 256, 256, 0, stream>>>(ef, dst, counts);
    expand_kernel<<<(NN + 255) / 256, 256, 0, stream>>>(counts, cntf);
    gemm_kernel<<<((NN + 127) / 128) * 2, 512, 0, stream>>>(h, cntf, emb, wsplit, b, out);
}

// Round 13
// 65.120 us; speedup vs baseline: 1.4388x; 1.4388x over previous
//
#include <hip/hip_runtime.h>

#define NN 100000
#define NE 600000
#define D 128
#define CW 16          // packed count words per node (125 x 4-bit)

// workspace byte offsets
#define OFF_CNTBF  6400000   // [NN][16] bf16 marginals (3.2 MB)
#define OFF_WSPLIT 9600000   // [2][128][128] bf16 W hi/lo (64 KB)
#define OFF_EFRAG  9665536   // [2][8][64][8] bf16 E^T A-frags (16 KB)

typedef __attribute__((ext_vector_type(8))) short bf16x8;
typedef __attribute__((ext_vector_type(4))) float f32x4;

__device__ __forceinline__ unsigned short f2bf(float x) {
    unsigned u = __float_as_uint(x);
    u += 0x7FFFu + ((u >> 16) & 1u);   // RNE
    return (unsigned short)(u >> 16);
}
__device__ __forceinline__ float bf2f(unsigned short s) {
    return __uint_as_float(((unsigned)s) << 16);
}
__device__ __forceinline__ unsigned pack2(unsigned short a, unsigned short b) {
    return (unsigned)a | ((unsigned)b << 16);
}

// ---------------------------------------------------------------------------
// prep: zero counts + W hi/lo split + E^T MFMA A-fragments (d-permuted)
// ---------------------------------------------------------------------------
__global__ __launch_bounds__(256) void prep_kernel(const float* __restrict__ W,
                                                   const float* __restrict__ emb,
                                                   unsigned char* __restrict__ ws) {
    int bid = blockIdx.x;
    if (bid < 1563) {
        int c = bid * 256 + threadIdx.x;            // int4 index into counts
        if (c < 400000) reinterpret_cast<int4*>(ws)[c] = make_int4(0, 0, 0, 0);
    } else if (bid < 1627) {
        int idx = (bid - 1563) * 256 + threadIdx.x; // 0..16383
        float w = W[idx];
        unsigned short hi = f2bf(w);
        unsigned short lo = f2bf(w - bf2f(hi));
        unsigned short* wsplit = (unsigned short*)(ws + OFF_WSPLIT);
        wsplit[idx] = hi;
        wsplit[16384 + idx] = lo;
    } else {
        int i = (bid - 1627) * 256 + threadIdx.x;   // 0..4095 : [t][lane][e]
        int e = i & 7, l = (i >> 3) & 63, t = (i >> 9) & 7;
        int r = l & 15, lg = l >> 4;
        int j = lg * 8 + e;
        int d = 32 * (t >> 1) + 8 * (r >> 2) + 4 * (t & 1) + (r & 3);
        float v = 0.0f;
        if (j < 15) v = emb[((j / 5) * 8 + (j % 5)) * D + d];
        unsigned short hi = f2bf(v);
        unsigned short lo = f2bf(v - bf2f(hi));
        unsigned short* ef = (unsigned short*)(ws + OFF_EFRAG);
        ef[i] = hi;
        ef[4096 + i] = lo;
    }
}

// ---------------------------------------------------------------------------
// hist: ONE packed atomic per edge (combo = f0*25+f1*5+f2, 4-bit counters)
// ---------------------------------------------------------------------------
__global__ __launch_bounds__(256) void hist_kernel(const int* __restrict__ ef,
                                                   const int* __restrict__ dst,
                                                   unsigned* __restrict__ counts) {
    int g = blockIdx.x * 256 + threadIdx.x;        // 4-edge group
    if (g >= NE / 4) return;
    int4 d4 = reinterpret_cast<const int4*>(dst)[g];
    int4 f0 = reinterpret_cast<const int4*>(ef)[g * 3 + 0];
    int4 f1 = reinterpret_cast<const int4*>(ef)[g * 3 + 1];
    int4 f2 = reinterpret_cast<const int4*>(ef)[g * 3 + 2];
    int fa[12] = {f0.x, f0.y, f0.z, f0.w, f1.x, f1.y, f1.z, f1.w,
                  f2.x, f2.y, f2.z, f2.w};
    int dd[4] = {d4.x, d4.y, d4.z, d4.w};
    #pragma unroll
    for (int i = 0; i < 4; ++i) {
        int combo = fa[i * 3] * 25 + fa[i * 3 + 1] * 5 + fa[i * 3 + 2];
        atomicAdd(counts + dd[i] * CW + (combo >> 3), 1u << ((combo & 7) * 4));
    }
}

// ---------------------------------------------------------------------------
// expand: unpack 125 combo nibbles -> 15 bf16 marginals (+pad), frag order
// ---------------------------------------------------------------------------
__global__ __launch_bounds__(256) void expand_kernel(const unsigned* __restrict__ counts,
                                                     unsigned short* __restrict__ cntbf) {
    int n = blockIdx.x * 256 + threadIdx.x;
    if (n >= NN) return;
    const unsigned* row = counts + n * CW;
    unsigned wd[16];
    #pragma unroll
    for (int i = 0; i < 4; ++i) {
        uint4 v = reinterpret_cast<const uint4*>(row)[i];
        wd[i * 4] = v.x; wd[i * 4 + 1] = v.y; wd[i * 4 + 2] = v.z; wd[i * 4 + 3] = v.w;
    }
    int mi[15];
    #pragma unroll
    for (int j = 0; j < 15; ++j) mi[j] = 0;
    #pragma unroll
    for (int c = 0; c < 125; ++c) {
        int cnt = (int)((wd[c >> 3] >> ((c & 7) * 4)) & 0xFu);
        mi[c / 25] += cnt;
        mi[5 + (c / 5) % 5] += cnt;
        mi[10 + c % 5] += cnt;
    }
    unsigned short o[16];
    #pragma unroll
    for (int j = 0; j < 15; ++j) o[j] = f2bf((float)mi[j]);  // exact (<256)
    o[15] = 0;
    uint4 u;
    u.x = pack2(o[0], o[1]);   u.y = pack2(o[2], o[3]);
    u.z = pack2(o[4], o[5]);   u.w = pack2(o[6], o[7]);
    reinterpret_cast<uint4*>(cntbf + n * 16)[0] = u;
    u.x = pack2(o[8], o[9]);   u.y = pack2(o[10], o[11]);
    u.z = pack2(o[12], o[13]); u.w = pack2(o[14], o[15]);
    reinterpret_cast<uint4*>(cntbf + n * 16)[1] = u;
}

// ---------------------------------------------------------------------------
// fused v13 = verified v5 minus (a) the VGPR-capping launch_bounds min-waves
// arg, (b) the unnecessary barrier between in-register pack and phase 2.
// Waves drift independently after the single W-stage barrier.
// ---------------------------------------------------------------------------
__global__ __launch_bounds__(512) void fused_kernel(
        const float* __restrict__ h,
        const unsigned short* __restrict__ cntbf,
        const unsigned short* __restrict__ efrag,
        const unsigned short* __restrict__ wsplit,
        const float* __restrict__ b,
        float* __restrict__ out) {
    __shared__ unsigned short sW[2][128 * 128];    // 65536 B, swizzled

    const int tid  = threadIdx.x;
    const int lane = tid & 63;
    const int w    = tid >> 6;
    const int n0   = blockIdx.x * 128;
    const int lr   = lane & 15;
    const int lg   = lane >> 4;

    char* sWb = (char*)&sW[0][0];

    // --- stage W hi/lo, swizzled: byte ^= (row&7)<<4 ---
    #pragma unroll
    for (int i = 0; i < 8; ++i) {
        int c  = tid + i * 512;                    // 0..4095 16B-chunks
        int p  = c >> 11;
        int r  = (c >> 4) & 127;
        int kc = c & 15;
        int byte = p * 32768 + r * 256 + ((kc * 16) ^ ((r & 7) << 4));
        *reinterpret_cast<uint4*>(sWb + byte) = reinterpret_cast<const uint4*>(wsplit)[c];
    }

    // --- phase 1: this wave's 16 nodes, all d ---
    const int node  = n0 + w * 16 + lr;
    const bool valid = node < NN;

    // h gather issued first (latency hides under efrag/MFMA chain)
    float hv[4][8];
    #pragma unroll
    for (int kk = 0; kk < 4; ++kk) {
        if (valid) {
            float4 h0 = *reinterpret_cast<const float4*>(h + node * D + kk * 32 + lg * 8);
            float4 h1 = *reinterpret_cast<const float4*>(h + node * D + kk * 32 + lg * 8 + 4);
            hv[kk][0] = h0.x; hv[kk][1] = h0.y; hv[kk][2] = h0.z; hv[kk][3] = h0.w;
            hv[kk][4] = h1.x; hv[kk][5] = h1.y; hv[kk][6] = h1.z; hv[kk][7] = h1.w;
        } else {
            #pragma unroll
            for (int e = 0; e < 8; ++e) hv[kk][e] = 0.0f;
        }
    }

    bf16x8 cfrag = {0, 0, 0, 0, 0, 0, 0, 0};
    if (valid && lg < 2)
        cfrag = *reinterpret_cast<const bf16x8*>(cntbf + node * 16 + lg * 8);

    f32x4 s[8];
    #pragma unroll
    for (int t = 0; t < 8; ++t) { f32x4 z = {0, 0, 0, 0}; s[t] = z; }
    #pragma unroll
    for (int p = 0; p < 2; ++p) {
        #pragma unroll
        for (int t = 0; t < 8; ++t) {
            bf16x8 ef = *reinterpret_cast<const bf16x8*>(efrag + p * 4096 + t * 512 + lane * 8);
            s[t] = __builtin_amdgcn_mfma_f32_16x16x32_bf16(ef, cfrag, s[t], 0, 0, 0);
        }
    }

    // pack A-fragments in-register (d(t,row) permutation makes this direct)
    bf16x8 afrag[4];
    #pragma unroll
    for (int kk = 0; kk < 4; ++kk) {
        unsigned short o[8];
        #pragma unroll
        for (int e = 0; e < 8; ++e)
            o[e] = f2bf(hv[kk][e] * s[kk * 2 + (e >> 2)][e & 3]);
        unsigned uo[4];
        uo[0] = pack2(o[0], o[1]); uo[1] = pack2(o[2], o[3]);
        uo[2] = pack2(o[4], o[5]); uo[3] = pack2(o[6], o[7]);
        afrag[kk] = *reinterpret_cast<bf16x8*>(uo);
    }
    __syncthreads();   // the ONE required barrier: sW visibility

    // --- phase 2: 16 nodes x 128 cols, W hi/lo 2-pass from LDS ---
    f32x4 acc[8];
    #pragma unroll
    for (int jb = 0; jb < 8; ++jb) {
        float bv = b[jb * 16 + lr];
        f32x4 t = {bv, bv, bv, bv};
        acc[jb] = t;
    }

    #pragma unroll
    for (int kk = 0; kk < 4; ++kk) {
        #pragma unroll
        for (int jb = 0; jb < 8; ++jb) {
            int brow  = jb * 16 + lr;
            int wbyte = brow * 256 + ((kk * 64 + lg * 16) ^ ((brow & 7) << 4));
            bf16x8 whi = *reinterpret_cast<const bf16x8*>(sWb + wbyte);
            bf16x8 wlo = *reinterpret_cast<const bf16x8*>(sWb + 32768 + wbyte);
            acc[jb] = __builtin_amdgcn_mfma_f32_16x16x32_bf16(afrag[kk], whi, acc[jb], 0, 0, 0);
            acc[jb] = __builtin_amdgcn_mfma_f32_16x16x32_bf16(afrag[kk], wlo, acc[jb], 0, 0, 0);
        }
    }

    #pragma unroll
    for (int jb = 0; jb < 8; ++jb) {
        int col = jb * 16 + lr;
        #pragma unroll
        for (int r = 0; r < 4; ++r) {
            int n2 = n0 + w * 16 + lg * 4 + r;
            if (n2 < NN) out[n2 * D + col] = acc[jb][r];
        }
    }
}

extern "C" void kernel_launch(void* const* d_in, const int* in_sizes, int n_in,
                              void* d_out, int out_size, void* d_ws, size_t ws_size,
                              hipStream_t stream) {
    const float* h   = (const float*)d_in[0];
    const int*   ef  = (const int*)d_in[1];
    const int*   dst = (const int*)d_in[2];
    const float* emb = (const float*)d_in[3];
    const float* W   = (const float*)d_in[4];
    const float* b   = (const float*)d_in[5];
    float*       out = (float*)d_out;

    unsigned char*  ws     = (unsigned char*)d_ws;
    unsigned*       counts = (unsigned*)ws;                         // 6.4 MB
    unsigned short* cntbf  = (unsigned short*)(ws + OFF_CNTBF);     // 3.2 MB
    unsigned short* wsplit = (unsigned short*)(ws + OFF_WSPLIT);    // 64 KB
    unsigned short* efr    = (unsigned short*)(ws + OFF_EFRAG);     // 16 KB

    prep_kernel<<<1563 + 64 + 16, 256, 0, stream>>>(W, emb, ws);
    hist_kernel<<<(NE / 4 + 255) / 256, 256, 0, stream>>>(ef, dst, counts);
    expand_kernel<<<(NN + 255) / 256, 256, 0, stream>>>(counts, cntbf);
    fused_kernel<<<(NN + 127) / 128, 512, 0, stream>>>(h, cntbf, efr, wsplit, b, out);
}